// Round 1
// 334.834 us; speedup vs baseline: 1.0176x; 1.0176x over previous
//
#include <hip/hip_runtime.h>
#include <hip/hip_bf16.h>

// Problem: N=64 batches, IO=64, H=1024, S=512
#define IOdim 64
#define Hdim  1024
#define Sdim  512
#define Nbat  64

typedef __bf16 bf16x8_t __attribute__((ext_vector_type(8)));
typedef float  f32x4_t  __attribute__((ext_vector_type(4)));

#define MFMA16(a, b, c) __builtin_amdgcn_mfma_f32_16x16x32_bf16((a), (b), (c), 0, 0, 0)

__device__ __forceinline__ unsigned short f2bf(float f) {
    return __builtin_bit_cast(unsigned short, (__bf16)f);
}
__device__ __forceinline__ bf16x8_t cvt8(float4 p0, float4 p1) {
    bf16x8_t b;
    b[0] = (__bf16)p0.x; b[1] = (__bf16)p0.y; b[2] = (__bf16)p0.z; b[3] = (__bf16)p0.w;
    b[4] = (__bf16)p1.x; b[5] = (__bf16)p1.y; b[6] = (__bf16)p1.z; b[7] = (__bf16)p1.w;
    return b;
}
// async 16B global->LDS (wave-uniform base + lane*16 dest)
__device__ __forceinline__ void async16(const void* g, void* l) {
    __builtin_amdgcn_global_load_lds(
        (const __attribute__((address_space(1))) void*)g,
        (__attribute__((address_space(3))) void*)l, 16, 0, 0);
}

// ---------------------------------------------------------------------------
__global__ __launch_bounds__(256) void cvt_kernel(const float* __restrict__ in,
                                                  unsigned short* __restrict__ outp,
                                                  int nElem) {
    int idx = blockIdx.x * 256 + threadIdx.x;
    if (idx < nElem) outp[idx] = f2bf(in[idx]);
}

__global__ __launch_bounds__(256) void transpose_cvt(const float* __restrict__ in,
                                                     unsigned short* __restrict__ outp,
                                                     int R, int C) {
    __shared__ float tile[32][33];
    int c0 = blockIdx.x * 32, r0 = blockIdx.y * 32;
    int tx = threadIdx.x, ty = threadIdx.y; // 32 x 8
#pragma unroll
    for (int i = 0; i < 4; i++) {
        int r = ty + i * 8;
        tile[r][tx] = in[(size_t)(r0 + r) * C + c0 + tx];
    }
    __syncthreads();
#pragma unroll
    for (int i = 0; i < 4; i++) {
        int r = ty + i * 8;
        outp[(size_t)(c0 + r) * R + r0 + tx] = f2bf(tile[tx][r]);
    }
}

// ---------------------------------------------------------------------------
// ob[i][h] = sum_k osb[i][k] * Wo[1024+k][h] + bo[h]   (shared across all n)
// Tiny GEMM (64x1024, K=1024): fragments straight from global (L2-resident).
__global__ __launch_bounds__(256) void ob_kernel(const unsigned short* __restrict__ osb,
                                                 const unsigned short* __restrict__ woT,
                                                 const float* __restrict__ bo,
                                                 float* __restrict__ ob) {
    int h0 = blockIdx.x * 64;
    int tid = threadIdx.x, lane = tid & 63, w = tid >> 6;
    int col = lane & 15, quad = lane >> 4;
    f32x4_t acc[4] = {};
    const unsigned short* bp  = woT + (size_t)(h0 + w * 16 + col) * 2048 + 1024 + quad * 8;
    const unsigned short* apb = osb + (size_t)col * 1024 + quad * 8;
    for (int kc = 0; kc < 1024; kc += 32) {
        bf16x8_t bfrag = *(const bf16x8_t*)(bp + kc);
#pragma unroll
        for (int a = 0; a < 4; a++) {
            bf16x8_t afrag = *(const bf16x8_t*)(apb + (size_t)a * 16 * 1024 + kc);
            acc[a] = MFMA16(bfrag, afrag, acc[a]); // D: m=h (quad*4+r), n=i (col)
        }
    }
#pragma unroll
    for (int a = 0; a < 4; a++)
#pragma unroll
        for (int r = 0; r < 4; r++) {
            int i = a * 16 + col;
            int h = h0 + w * 16 + quad * 4 + r;
            ob[(size_t)i * Hdim + h] = acc[a][r] + bo[h];
        }
}

// ---------------------------------------------------------------------------
// scores: attn[n][i][s] = sum_h output_set[i][h] * states[n][s][h]
// m97-style async16 staging. NEW: XOR-swizzled LDS (seg ^= row&7) applied as
// pre-swizzled GLOBAL source + swizzled READ (linear async16 dest, rule #21).
// Fixes the 16-way bank conflict of the 256B/128B-stride row-major tiles.
__global__ __launch_bounds__(256) void scores_kernel(const float* __restrict__ states,
                                                     const unsigned short* __restrict__ osb,
                                                     float* __restrict__ attnf) {
    __shared__ float Bst[64 * 64];           // [s 64][k 64] fp32, 16 KB
    __shared__ unsigned short Ast[64 * 64];  // [i 64][k 64] bf16, 8 KB
    int n = blockIdx.y, s0 = blockIdx.x * 64;
    int tid = threadIdx.x, lane = tid & 63, w = tid >> 6;
    int col = lane & 15, quad = lane >> 4;
    // staging: B row t>>4 (+16j), seg (t&15)^(row&7); A row t>>3 (+32j), seg (t&7)^(row&7)
    const float* bsrc = states + ((size_t)(n * Sdim + s0 + (tid >> 4)) << 10)
                      + (((tid & 15) ^ ((tid >> 4) & 7)) << 2);
    const unsigned short* asrc = osb + ((size_t)(tid >> 3) << 10)
                      + (((tid & 7) ^ ((tid >> 3) & 7)) << 3);
    float* bdst = Bst + tid * 4;             // linear dest, byte t*16, +j*4096B
    unsigned short* adst = Ast + tid * 8;
    int xs = col & 7;                        // read-side XOR (row&7 of all frag rows)
    f32x4_t acc[4] = {};
    for (int kc = 0; kc < Hdim; kc += 64) {
#pragma unroll
        for (int j = 0; j < 4; j++)
            async16(bsrc + ((size_t)j << 14) + kc, bdst + j * 1024);
#pragma unroll
        for (int j = 0; j < 2; j++)
            async16(asrc + ((size_t)j << 15) + kc, adst + j * 2048);
        __syncthreads();
#pragma unroll
        for (int kk = 0; kk < 2; kk++) {
            int R = w * 16 + col;
            int sg = kk * 8 + quad * 2;      // 16B-seg index within 16-seg fp32 row
            float4 f0 = *(const float4*)(Bst + R * 64 + ((sg ^ xs) << 2));
            float4 f1 = *(const float4*)(Bst + R * 64 + (((sg + 1) ^ xs) << 2));
            bf16x8_t bfrag = cvt8(f0, f1);
#pragma unroll
            for (int a = 0; a < 4; a++) {
                bf16x8_t afrag = *(const bf16x8_t*)(Ast + (a * 16 + col) * 64
                                                    + (((kk * 4 + quad) ^ xs) << 3));
                acc[a] = MFMA16(afrag, bfrag, acc[a]);
            }
        }
        __syncthreads();
    }
    // C/D: col=lane&15 -> s, row=quad*4+r -> i (within a-group)
    float* obp = attnf + (size_t)(n * IOdim) * Sdim + s0 + w * 16 + col;
#pragma unroll
    for (int a = 0; a < 4; a++)
#pragma unroll
        for (int r = 0; r < 4; r++) {
            int i = a * 16 + quad * 4 + r;
            obp[(size_t)i * Sdim] = acc[a][r];
        }
}

// ---------------------------------------------------------------------------
__global__ __launch_bounds__(256) void softmax_kernel(const float* __restrict__ attnf,
                                                      unsigned short* __restrict__ attnb) {
    int row = blockIdx.x * 4 + (threadIdx.x >> 6);
    int lane = threadIdx.x & 63;
    const float* p = attnf + (size_t)row * Sdim + lane * 8;
    float4 v0 = ((const float4*)p)[0];
    float4 v1 = ((const float4*)p)[1];
    float v[8] = {v0.x, v0.y, v0.z, v0.w, v1.x, v1.y, v1.z, v1.w};
    float m = v[0];
#pragma unroll
    for (int j = 1; j < 8; j++) m = fmaxf(m, v[j]);
#pragma unroll
    for (int off = 32; off > 0; off >>= 1) m = fmaxf(m, __shfl_xor(m, off));
    float sum = 0.f;
#pragma unroll
    for (int j = 0; j < 8; j++) { v[j] = __expf(v[j] - m); sum += v[j]; }
#pragma unroll
    for (int off = 32; off > 0; off >>= 1) sum += __shfl_xor(sum, off);
    float inv = 1.0f / sum;
    union { unsigned short u[8]; uint4 q; } res;
#pragma unroll
    for (int j = 0; j < 8; j++) res.u[j] = f2bf(v[j] * inv);
    *(uint4*)(attnb + (size_t)row * Sdim + lane * 8) = res.q;
}

// ---------------------------------------------------------------------------
// mix[n][i][h] = sum_s attn[n][i][s] * states[n][s][h]
// (R6-proven version) statesT chunk through LDS (stride-72 pad = conflict-free);
// next chunk's strided loads prefetched into registers before the barrier.
__global__ __launch_bounds__(256) void mix_kernel(const float* __restrict__ states,
                                                  const unsigned short* __restrict__ attnb,
                                                  unsigned short* __restrict__ mixb) {
    __shared__ unsigned short Tlds[64 * 72]; // [h 64][s 64] stride 72
    int n = blockIdx.y, h0 = blockIdx.x * 64;
    int tid = threadIdx.x, lane = tid & 63, g = tid >> 6;
    int col = lane & 15, quad = lane >> 4;
    f32x4_t acc0 = {0,0,0,0}, acc1 = {0,0,0,0}, acc2 = {0,0,0,0}, acc3 = {0,0,0,0};
    const unsigned short* ap = attnb + (size_t)(n * IOdim + col) * Sdim + quad * 8;
    const float* sbase = states + (size_t)n * Sdim * Hdim + h0 + lane;
    float cur[16];
#pragma unroll
    for (int rep = 0; rep < 16; rep++) cur[rep] = sbase[(size_t)(g * 16 + rep) * Hdim];
    for (int sc = 0; sc < Sdim; sc += 64) {
        union { unsigned short u[16]; uint4 q[2]; } pk;
#pragma unroll
        for (int rep = 0; rep < 16; rep++) pk.u[rep] = f2bf(cur[rep]);
        if (sc) __syncthreads(); // prev chunk's readers done before overwrite
        *(uint4*)(Tlds + lane * 72 + g * 16)     = pk.q[0];
        *(uint4*)(Tlds + lane * 72 + g * 16 + 8) = pk.q[1];
        if (sc + 64 < Sdim) {
#pragma unroll
            for (int rep = 0; rep < 16; rep++)
                cur[rep] = sbase[(size_t)(sc + 64 + g * 16 + rep) * Hdim];
        }
        __syncthreads();
#pragma unroll
        for (int ks = 0; ks < 64; ks += 32) {
            bf16x8_t b  = *(const bf16x8_t*)(Tlds + (g * 16 + col) * 72 + ks + quad * 8);
            bf16x8_t a0 = *(const bf16x8_t*)(ap + sc + ks);
            bf16x8_t a1 = *(const bf16x8_t*)(ap + 16 * Sdim + sc + ks);
            bf16x8_t a2 = *(const bf16x8_t*)(ap + 32 * Sdim + sc + ks);
            bf16x8_t a3 = *(const bf16x8_t*)(ap + 48 * Sdim + sc + ks);
            acc0 = MFMA16(a0, b, acc0);
            acc1 = MFMA16(a1, b, acc1);
            acc2 = MFMA16(a2, b, acc2);
            acc3 = MFMA16(a3, b, acc3);
        }
    }
    f32x4_t accs[4] = {acc0, acc1, acc2, acc3};
    int h = h0 + g * 16 + col;
#pragma unroll
    for (int ai = 0; ai < 4; ai++)
#pragma unroll
        for (int r = 0; r < 4; r++) {
            int i = ai * 16 + quad * 4 + r;
            mixb[(size_t)(n * IOdim + i) * Hdim + h] = f2bf(accs[ai][r]);
        }
}

// ---------------------------------------------------------------------------
// out_gemm: tb[n*64+i][h] = tanh( mix[n,i]·Wo1[:,h] + OB[i][h] )
// NEW: K halved to 1024 (osb@Wo2 hoisted to ob_kernel), BK=64 (m97 shape,
// 16 MFMA/wave per barrier-pair), XOR-swizzled LDS tiles (2-way = free).
__global__ __launch_bounds__(256) void out_gemm(const unsigned short* __restrict__ mixb,
                                                const unsigned short* __restrict__ woT,
                                                const float* __restrict__ ob,
                                                unsigned short* __restrict__ tb) {
    __shared__ unsigned short Ald[128 * 64]; // 16 KB
    __shared__ unsigned short Bld[64 * 64];  // 8 KB
    int h0 = blockIdx.x * 64, r0 = blockIdx.y * 128;
    int tid = threadIdx.x, lane = tid & 63, w = tid >> 6;
    int col = lane & 15, quad = lane >> 4;
    int wx = w & 1, wy = w >> 1;
    // staging: row t>>3 (+32j), seg (t&7)^(row&7), 8 segs of 16B per 64-col row
    int sw = ((tid & 7) ^ ((tid >> 3) & 7)) * 8;
    const unsigned short* m1 = mixb + (size_t)(r0 + (tid >> 3)) * Hdim + sw;
    const unsigned short* w1 = woT + (size_t)(h0 + (tid >> 3)) * 2048 + sw;
    unsigned short* lA = Ald + (size_t)tid * 8;
    unsigned short* lB = Bld + (size_t)tid * 8;
    int xs = col & 7;
    f32x4_t acc[4][2] = {};
    for (int kc = 0; kc < 1024; kc += 64) {
#pragma unroll
        for (int j = 0; j < 4; j++)
            async16(m1 + (size_t)j * 32 * Hdim + kc, lA + j * 2048);
#pragma unroll
        for (int j = 0; j < 2; j++)
            async16(w1 + (size_t)j * 32 * 2048 + kc, lB + j * 2048);
        __syncthreads();
#pragma unroll
        for (int kk = 0; kk < 2; kk++) {
            bf16x8_t bfr[2];
#pragma unroll
            for (int ni = 0; ni < 2; ni++)
                bfr[ni] = *(const bf16x8_t*)(Bld + (wx * 32 + ni * 16 + col) * 64
                                             + (((kk * 4 + quad) ^ xs) << 3));
#pragma unroll
            for (int mi = 0; mi < 4; mi++) {
                bf16x8_t af = *(const bf16x8_t*)(Ald + (wy * 64 + mi * 16 + col) * 64
                                                 + (((kk * 4 + quad) ^ xs) << 3));
#pragma unroll
                for (int ni = 0; ni < 2; ni++)
                    acc[mi][ni] = MFMA16(af, bfr[ni], acc[mi][ni]);
            }
        }
        __syncthreads();
    }
#pragma unroll
    for (int ni = 0; ni < 2; ni++) {
        int h = h0 + wx * 32 + ni * 16 + col;
#pragma unroll
        for (int mi = 0; mi < 4; mi++)
#pragma unroll
            for (int r = 0; r < 4; r++) {
                int rr = r0 + wy * 64 + mi * 16 + quad * 4 + r;
                int i = rr & 63; // rows are n*64+i
                tb[(size_t)rr * Hdim + h] = f2bf(tanhf(acc[mi][ni][r] + ob[(size_t)i * Hdim + h]));
            }
    }
}

// ---------------------------------------------------------------------------
// final: partial[blk][n][j] = sum_{k in 128-chunk} t[n][k] * Wc[k][j]
__global__ __launch_bounds__(256) void final_gemm(const unsigned short* __restrict__ tb,
                                                  const unsigned short* __restrict__ wcT,
                                                  float* __restrict__ partials) {
    int kc0 = blockIdx.x * 128;
    int tid = threadIdx.x, lane = tid & 63, g = tid >> 6;
    int col = lane & 15, quad = lane >> 4;
    f32x4_t acc0 = {0,0,0,0}, acc1 = {0,0,0,0}, acc2 = {0,0,0,0}, acc3 = {0,0,0,0};
    const unsigned short* ap = tb + (size_t)col * 65536 + kc0 + quad * 8;
    const unsigned short* bp = wcT + (size_t)(g * 16 + col) * 65536 + kc0 + quad * 8;
    bf16x8_t B[2], A0[2], A1[2], A2[2], A3[2];
#pragma unroll
    for (int t = 0; t < 2; t++) {
        B[t]  = *(const bf16x8_t*)(bp + t * 32);
        A0[t] = *(const bf16x8_t*)(ap + t * 32);
        A1[t] = *(const bf16x8_t*)(ap + (size_t)16 * 65536 + t * 32);
        A2[t] = *(const bf16x8_t*)(ap + (size_t)32 * 65536 + t * 32);
        A3[t] = *(const bf16x8_t*)(ap + (size_t)48 * 65536 + t * 32);
    }
#pragma unroll
    for (int c = 0; c < 4; c++) {
        int p = c & 1;
        acc0 = MFMA16(A0[p], B[p], acc0);
        acc1 = MFMA16(A1[p], B[p], acc1);
        acc2 = MFMA16(A2[p], B[p], acc2);
        acc3 = MFMA16(A3[p], B[p], acc3);
        if (c + 2 < 4) {
            int kn = (c + 2) * 32;
            B[p]  = *(const bf16x8_t*)(bp + kn);
            A0[p] = *(const bf16x8_t*)(ap + kn);
            A1[p] = *(const bf16x8_t*)(ap + (size_t)16 * 65536 + kn);
            A2[p] = *(const bf16x8_t*)(ap + (size_t)32 * 65536 + kn);
            A3[p] = *(const bf16x8_t*)(ap + (size_t)48 * 65536 + kn);
        }
    }
    f32x4_t accs[4] = {acc0, acc1, acc2, acc3};
    int j = g * 16 + col;
    float* pb = partials + blockIdx.x * 4096;
#pragma unroll
    for (int ai = 0; ai < 4; ai++)
#pragma unroll
        for (int r = 0; r < 4; r++) {
            int nn = ai * 16 + quad * 4 + r;
            pb[nn * 64 + j] = accs[ai][r];
        }
}

// NEW: grid 64 (was 16 -> only 16 CUs -> 0.4 TB/s ceiling). Each block owns 64
// outputs; 4 waves split the 512 partial-chunks, LDS combine.
__global__ __launch_bounds__(256) void reduce_kernel(const float* __restrict__ partials,
                                                     const float* __restrict__ bc,
                                                     float* __restrict__ out) {
    __shared__ float red[4][64];
    int tid = threadIdx.x, lane = tid & 63, w = tid >> 6;
    int idx = blockIdx.x * 64 + lane;
    float s = 0.f;
#pragma unroll 4
    for (int c = w; c < 512; c += 4) s += partials[(size_t)c * 4096 + idx];
    red[w][lane] = s;
    __syncthreads();
    if (w == 0)
        out[idx] = red[0][lane] + red[1][lane] + red[2][lane] + red[3][lane] + bc[idx & 63];
}

// ---------------------------------------------------------------------------
extern "C" void kernel_launch(void* const* d_in, const int* in_sizes, int n_in,
                              void* d_out, int out_size, void* d_ws, size_t ws_size,
                              hipStream_t stream) {
    const float* states     = (const float*)d_in[0]; // [64][512][1024]
    const float* output_set = (const float*)d_in[1]; // [64][1024]
    const float* Wo         = (const float*)d_in[2]; // [2048][1024]
    const float* bo         = (const float*)d_in[3]; // [1024]
    const float* Wc         = (const float*)d_in[4]; // [65536][64]
    const float* bc         = (const float*)d_in[5]; // [64]
    float* out = (float*)d_out;                      // [64][64]

    char* ws = (char*)d_ws;
    // ws footprint ~40.6 MB. parts ALIASES attnf (disjoint lifetimes).
    float*          attnf = (float*)ws;                                       // 8 MB
    float*          parts = (float*)ws;                                       // 8 MB (reuses attnf)
    unsigned short* attnb = (unsigned short*)(ws + (8u  << 20));              // 4 MB
    unsigned short* mixb  = (unsigned short*)(ws + (12u << 20));              // 8 MB
    unsigned short* tb    = (unsigned short*)(ws + (20u << 20));              // 8 MB
    unsigned short* woT   = (unsigned short*)(ws + (28u << 20));              // 4 MB
    unsigned short* osb   = (unsigned short*)(ws + (32u << 20));              // 128 KB
    unsigned short* wcT   = (unsigned short*)(ws + (32u << 20) + (1u << 18)); // 8 MB
    float*          obuf  = (float*)(ws + (40u << 20) + (1u << 18));          // 256 KB

    cvt_kernel<<<dim3(IOdim * Hdim / 256), dim3(256), 0, stream>>>(output_set, osb, IOdim * Hdim);
    transpose_cvt<<<dim3(Hdim / 32, 2048 / 32), dim3(32, 8), 0, stream>>>(Wo, woT, 2048, Hdim);
    transpose_cvt<<<dim3(64 / 32, 65536 / 32), dim3(32, 8), 0, stream>>>(Wc, wcT, 65536, 64);
    ob_kernel<<<dim3(Hdim / 64), dim3(256), 0, stream>>>(osb, woT, bo, obuf);
    scores_kernel<<<dim3(Sdim / 64, Nbat), dim3(256), 0, stream>>>(states, osb, attnf);
    softmax_kernel<<<dim3(Nbat * IOdim / 4), dim3(256), 0, stream>>>(attnf, attnb);
    mix_kernel<<<dim3(Hdim / 64, Nbat), dim3(256), 0, stream>>>(states, attnb, mixb);
    out_gemm<<<dim3(Hdim / 64, Nbat * IOdim / 128), dim3(256), 0, stream>>>(mixb, woT, obuf, tb);
    final_gemm<<<dim3(512), dim3(256), 0, stream>>>(tb, wcT, parts);
    reduce_kernel<<<dim3(64), dim3(256), 0, stream>>>(parts, bc, out);
}

// Round 2
// 327.472 us; speedup vs baseline: 1.0405x; 1.0225x over previous
//
#include <hip/hip_runtime.h>
#include <hip/hip_bf16.h>

// Problem: N=64 batches, IO=64, H=1024, S=512
#define IOdim 64
#define Hdim  1024
#define Sdim  512
#define Nbat  64

typedef __bf16 bf16x8_t __attribute__((ext_vector_type(8)));
typedef float  f32x4_t  __attribute__((ext_vector_type(4)));

#define MFMA16(a, b, c) __builtin_amdgcn_mfma_f32_16x16x32_bf16((a), (b), (c), 0, 0, 0)

__device__ __forceinline__ unsigned short f2bf(float f) {
    return __builtin_bit_cast(unsigned short, (__bf16)f);
}
__device__ __forceinline__ bf16x8_t cvt8(float4 p0, float4 p1) {
    bf16x8_t b;
    b[0] = (__bf16)p0.x; b[1] = (__bf16)p0.y; b[2] = (__bf16)p0.z; b[3] = (__bf16)p0.w;
    b[4] = (__bf16)p1.x; b[5] = (__bf16)p1.y; b[6] = (__bf16)p1.z; b[7] = (__bf16)p1.w;
    return b;
}
// async 16B global->LDS (wave-uniform base + lane*16 dest)
__device__ __forceinline__ void async16(const void* g, void* l) {
    __builtin_amdgcn_global_load_lds(
        (const __attribute__((address_space(1))) void*)g,
        (__attribute__((address_space(3))) void*)l, 16, 0, 0);
}
// counted drain + raw barrier (avoids __syncthreads' full vmcnt(0)+lgkmcnt(0)
// being the ONLY sync point; here the drain sits AFTER compute, T3-minimum)
#define PIPE_SYNC() do { \
    asm volatile("s_waitcnt vmcnt(0)" ::: "memory"); \
    __builtin_amdgcn_s_barrier(); \
} while (0)

// ---------------------------------------------------------------------------
__global__ __launch_bounds__(256) void cvt_kernel(const float* __restrict__ in,
                                                  unsigned short* __restrict__ outp,
                                                  int nElem) {
    int idx = blockIdx.x * 256 + threadIdx.x;
    if (idx < nElem) outp[idx] = f2bf(in[idx]);
}

__global__ __launch_bounds__(256) void transpose_cvt(const float* __restrict__ in,
                                                     unsigned short* __restrict__ outp,
                                                     int R, int C) {
    __shared__ float tile[32][33];
    int c0 = blockIdx.x * 32, r0 = blockIdx.y * 32;
    int tx = threadIdx.x, ty = threadIdx.y; // 32 x 8
#pragma unroll
    for (int i = 0; i < 4; i++) {
        int r = ty + i * 8;
        tile[r][tx] = in[(size_t)(r0 + r) * C + c0 + tx];
    }
    __syncthreads();
#pragma unroll
    for (int i = 0; i < 4; i++) {
        int r = ty + i * 8;
        outp[(size_t)(c0 + r) * R + r0 + tx] = f2bf(tile[tx][r]);
    }
}

// ---------------------------------------------------------------------------
// ob[i][h] = sum_k osb[i][k] * Wo[1024+k][h] + bo[h]   (shared across all n)
__global__ __launch_bounds__(256) void ob_kernel(const unsigned short* __restrict__ osb,
                                                 const unsigned short* __restrict__ woT,
                                                 const float* __restrict__ bo,
                                                 float* __restrict__ ob) {
    int h0 = blockIdx.x * 64;
    int tid = threadIdx.x, lane = tid & 63, w = tid >> 6;
    int col = lane & 15, quad = lane >> 4;
    f32x4_t acc[4] = {};
    const unsigned short* bp  = woT + (size_t)(h0 + w * 16 + col) * 2048 + 1024 + quad * 8;
    const unsigned short* apb = osb + (size_t)col * 1024 + quad * 8;
    for (int kc = 0; kc < 1024; kc += 32) {
        bf16x8_t bfrag = *(const bf16x8_t*)(bp + kc);
#pragma unroll
        for (int a = 0; a < 4; a++) {
            bf16x8_t afrag = *(const bf16x8_t*)(apb + (size_t)a * 16 * 1024 + kc);
            acc[a] = MFMA16(bfrag, afrag, acc[a]); // D: m=h (quad*4+r), n=i (col)
        }
    }
#pragma unroll
    for (int a = 0; a < 4; a++)
#pragma unroll
        for (int r = 0; r < 4; r++) {
            int i = a * 16 + col;
            int h = h0 + w * 16 + quad * 4 + r;
            ob[(size_t)i * Hdim + h] = acc[a][r] + bo[h];
        }
}

// ---------------------------------------------------------------------------
// scores: attn[n][i][s] = sum_h output_set[i][h] * states[n][s][h]
// NEW (R2): 2-phase double-buffered pipeline. Stage chunk t+1 FIRST, compute
// chunk t, then ONE counted drain + raw barrier per chunk (was: drain-before-
// compute via __syncthreads x2 -> HBM latency fully exposed every chunk).
// XOR-swizzled LDS kept (pre-swizzled global src, swizzled read; rule #21).
__global__ __launch_bounds__(256) void scores_kernel(const float* __restrict__ states,
                                                     const unsigned short* __restrict__ osb,
                                                     float* __restrict__ attnf) {
    __shared__ float Bst[2][64 * 64];           // 2 x 16 KB
    __shared__ unsigned short Ast[2][64 * 64];  // 2 x 8 KB   (48 KB total)
    int n = blockIdx.y, s0 = blockIdx.x * 64;
    int tid = threadIdx.x, lane = tid & 63, w = tid >> 6;
    int col = lane & 15, quad = lane >> 4;
    const float* bsrc = states + ((size_t)(n * Sdim + s0 + (tid >> 4)) << 10)
                      + (((tid & 15) ^ ((tid >> 4) & 7)) << 2);
    const unsigned short* asrc = osb + ((size_t)(tid >> 3) << 10)
                      + (((tid & 7) ^ ((tid >> 3) & 7)) << 3);
    int xs = col & 7;
    int R = w * 16 + col;
    float* B0 = Bst[0]; float* B1 = Bst[1];
    unsigned short* A0 = Ast[0]; unsigned short* A1 = Ast[1];
    f32x4_t acc[4] = {};

#define SC_STAGE(kc, Bb, Ab) do { \
    _Pragma("unroll") for (int j = 0; j < 4; j++) \
        async16(bsrc + ((size_t)j << 14) + (kc), (Bb) + tid * 4 + j * 1024); \
    _Pragma("unroll") for (int j = 0; j < 2; j++) \
        async16(asrc + ((size_t)j << 15) + (kc), (Ab) + tid * 8 + j * 2048); \
} while (0)

    SC_STAGE(0, B0, A0);
    PIPE_SYNC();
    for (int t = 0; t < 16; ++t) {
        if (t + 1 < 16) SC_STAGE((t + 1) * 64, B1, A1);
#pragma unroll
        for (int kk = 0; kk < 2; kk++) {
            int sg = kk * 8 + quad * 2;      // 16B-seg index within 16-seg fp32 row
            float4 f0 = *(const float4*)(B0 + R * 64 + ((sg ^ xs) << 2));
            float4 f1 = *(const float4*)(B0 + R * 64 + (((sg + 1) ^ xs) << 2));
            bf16x8_t bfrag = cvt8(f0, f1);
#pragma unroll
            for (int a = 0; a < 4; a++) {
                bf16x8_t afrag = *(const bf16x8_t*)(A0 + (a * 16 + col) * 64
                                                    + (((kk * 4 + quad) ^ xs) << 3));
                acc[a] = MFMA16(afrag, bfrag, acc[a]);
            }
        }
        PIPE_SYNC();
        float* tB = B0; B0 = B1; B1 = tB;
        unsigned short* tA = A0; A0 = A1; A1 = tA;
    }
#undef SC_STAGE
    // C/D: col=lane&15 -> s, row=quad*4+r -> i (within a-group)
    float* obp = attnf + (size_t)(n * IOdim) * Sdim + s0 + w * 16 + col;
#pragma unroll
    for (int a = 0; a < 4; a++)
#pragma unroll
        for (int r = 0; r < 4; r++) {
            int i = a * 16 + quad * 4 + r;
            obp[(size_t)i * Sdim] = acc[a][r];
        }
}

// ---------------------------------------------------------------------------
__global__ __launch_bounds__(256) void softmax_kernel(const float* __restrict__ attnf,
                                                      unsigned short* __restrict__ attnb) {
    int row = blockIdx.x * 4 + (threadIdx.x >> 6);
    int lane = threadIdx.x & 63;
    const float* p = attnf + (size_t)row * Sdim + lane * 8;
    float4 v0 = ((const float4*)p)[0];
    float4 v1 = ((const float4*)p)[1];
    float v[8] = {v0.x, v0.y, v0.z, v0.w, v1.x, v1.y, v1.z, v1.w};
    float m = v[0];
#pragma unroll
    for (int j = 1; j < 8; j++) m = fmaxf(m, v[j]);
#pragma unroll
    for (int off = 32; off > 0; off >>= 1) m = fmaxf(m, __shfl_xor(m, off));
    float sum = 0.f;
#pragma unroll
    for (int j = 0; j < 8; j++) { v[j] = __expf(v[j] - m); sum += v[j]; }
#pragma unroll
    for (int off = 32; off > 0; off >>= 1) sum += __shfl_xor(sum, off);
    float inv = 1.0f / sum;
    union { unsigned short u[8]; uint4 q; } res;
#pragma unroll
    for (int j = 0; j < 8; j++) res.u[j] = f2bf(v[j] * inv);
    *(uint4*)(attnb + (size_t)row * Sdim + lane * 8) = res.q;
}

// ---------------------------------------------------------------------------
// mix[n][i][h] = sum_s attn[n][i][s] * states[n][s][h]
// NEW (R2): double-buffered Tlds -> ONE __syncthreads per chunk (was 2).
// Reg-prefetch of next chunk's strided loads kept.
__global__ __launch_bounds__(256) void mix_kernel(const float* __restrict__ states,
                                                  const unsigned short* __restrict__ attnb,
                                                  unsigned short* __restrict__ mixb) {
    __shared__ unsigned short Tlds[2][64 * 72]; // 2 x 9 KB, [h 64][s 64] stride 72
    int n = blockIdx.y, h0 = blockIdx.x * 64;
    int tid = threadIdx.x, lane = tid & 63, g = tid >> 6;
    int col = lane & 15, quad = lane >> 4;
    f32x4_t acc0 = {0,0,0,0}, acc1 = {0,0,0,0}, acc2 = {0,0,0,0}, acc3 = {0,0,0,0};
    const unsigned short* ap = attnb + (size_t)(n * IOdim + col) * Sdim + quad * 8;
    const float* sbase = states + (size_t)n * Sdim * Hdim + h0 + lane;
    float cur[16];
#pragma unroll
    for (int rep = 0; rep < 16; rep++) cur[rep] = sbase[(size_t)(g * 16 + rep) * Hdim];
    for (int t = 0; t < 8; ++t) {
        int sc = t * 64;
        unsigned short* Tb = Tlds[t & 1];
        union { unsigned short u[16]; uint4 q[2]; } pk;
#pragma unroll
        for (int rep = 0; rep < 16; rep++) pk.u[rep] = f2bf(cur[rep]);
        *(uint4*)(Tb + lane * 72 + g * 16)     = pk.q[0];
        *(uint4*)(Tb + lane * 72 + g * 16 + 8) = pk.q[1];
        if (t + 1 < 8) {
#pragma unroll
            for (int rep = 0; rep < 16; rep++)
                cur[rep] = sbase[(size_t)(sc + 64 + g * 16 + rep) * Hdim];
        }
        __syncthreads();
#pragma unroll
        for (int ks = 0; ks < 64; ks += 32) {
            bf16x8_t b  = *(const bf16x8_t*)(Tb + (g * 16 + col) * 72 + ks + quad * 8);
            bf16x8_t a0 = *(const bf16x8_t*)(ap + sc + ks);
            bf16x8_t a1 = *(const bf16x8_t*)(ap + 16 * Sdim + sc + ks);
            bf16x8_t a2 = *(const bf16x8_t*)(ap + 32 * Sdim + sc + ks);
            bf16x8_t a3 = *(const bf16x8_t*)(ap + 48 * Sdim + sc + ks);
            acc0 = MFMA16(a0, b, acc0);
            acc1 = MFMA16(a1, b, acc1);
            acc2 = MFMA16(a2, b, acc2);
            acc3 = MFMA16(a3, b, acc3);
        }
    }
    f32x4_t accs[4] = {acc0, acc1, acc2, acc3};
    int h = h0 + g * 16 + col;
#pragma unroll
    for (int ai = 0; ai < 4; ai++)
#pragma unroll
        for (int r = 0; r < 4; r++) {
            int i = ai * 16 + quad * 4 + r;
            mixb[(size_t)(n * IOdim + i) * Hdim + h] = f2bf(accs[ai][r]);
        }
}

// ---------------------------------------------------------------------------
// out_gemm: tb[n*64+i][h] = tanh( mix[n,i]·Wo1[:,h] + OB[i][h] )
// NEW (R2): same 2-phase double-buffered pipeline as scores_kernel.
__global__ __launch_bounds__(256) void out_gemm(const unsigned short* __restrict__ mixb,
                                                const unsigned short* __restrict__ woT,
                                                const float* __restrict__ ob,
                                                unsigned short* __restrict__ tb) {
    __shared__ unsigned short Ald[2][128 * 64]; // 2 x 16 KB
    __shared__ unsigned short Bld[2][64 * 64];  // 2 x 8 KB   (48 KB total)
    int h0 = blockIdx.x * 64, r0 = blockIdx.y * 128;
    int tid = threadIdx.x, lane = tid & 63, w = tid >> 6;
    int col = lane & 15, quad = lane >> 4;
    int wx = w & 1, wy = w >> 1;
    int sw = ((tid & 7) ^ ((tid >> 3) & 7)) * 8;
    const unsigned short* m1 = mixb + (size_t)(r0 + (tid >> 3)) * Hdim + sw;
    const unsigned short* w1 = woT + (size_t)(h0 + (tid >> 3)) * 2048 + sw;
    int xs = col & 7;
    unsigned short* A0 = Ald[0]; unsigned short* A1 = Ald[1];
    unsigned short* B0 = Bld[0]; unsigned short* B1 = Bld[1];
    f32x4_t acc[4][2] = {};

#define OG_STAGE(kc, Ab, Bb) do { \
    _Pragma("unroll") for (int j = 0; j < 4; j++) \
        async16(m1 + (size_t)j * 32 * Hdim + (kc), (Ab) + tid * 8 + j * 2048); \
    _Pragma("unroll") for (int j = 0; j < 2; j++) \
        async16(w1 + (size_t)j * 32 * 2048 + (kc), (Bb) + tid * 8 + j * 2048); \
} while (0)

    OG_STAGE(0, A0, B0);
    PIPE_SYNC();
    for (int t = 0; t < 16; ++t) {
        if (t + 1 < 16) OG_STAGE((t + 1) * 64, A1, B1);
#pragma unroll
        for (int kk = 0; kk < 2; kk++) {
            bf16x8_t bfr[2];
#pragma unroll
            for (int ni = 0; ni < 2; ni++)
                bfr[ni] = *(const bf16x8_t*)(B0 + (wx * 32 + ni * 16 + col) * 64
                                             + (((kk * 4 + quad) ^ xs) << 3));
#pragma unroll
            for (int mi = 0; mi < 4; mi++) {
                bf16x8_t af = *(const bf16x8_t*)(A0 + (wy * 64 + mi * 16 + col) * 64
                                                 + (((kk * 4 + quad) ^ xs) << 3));
#pragma unroll
                for (int ni = 0; ni < 2; ni++)
                    acc[mi][ni] = MFMA16(af, bfr[ni], acc[mi][ni]);
            }
        }
        PIPE_SYNC();
        unsigned short* tp;
        tp = A0; A0 = A1; A1 = tp;
        tp = B0; B0 = B1; B1 = tp;
    }
#undef OG_STAGE
#pragma unroll
    for (int ni = 0; ni < 2; ni++) {
        int h = h0 + wx * 32 + ni * 16 + col;
#pragma unroll
        for (int mi = 0; mi < 4; mi++)
#pragma unroll
            for (int r = 0; r < 4; r++) {
                int rr = r0 + wy * 64 + mi * 16 + quad * 4 + r;
                int i = rr & 63; // rows are n*64+i
                tb[(size_t)rr * Hdim + h] = f2bf(tanhf(acc[mi][ni][r] + ob[(size_t)i * Hdim + h]));
            }
    }
}

// ---------------------------------------------------------------------------
// final: partial[blk][n][j] = sum_{k in 128-chunk} t[n][k] * Wc[k][j]
__global__ __launch_bounds__(256) void final_gemm(const unsigned short* __restrict__ tb,
                                                  const unsigned short* __restrict__ wcT,
                                                  float* __restrict__ partials) {
    int kc0 = blockIdx.x * 128;
    int tid = threadIdx.x, lane = tid & 63, g = tid >> 6;
    int col = lane & 15, quad = lane >> 4;
    f32x4_t acc0 = {0,0,0,0}, acc1 = {0,0,0,0}, acc2 = {0,0,0,0}, acc3 = {0,0,0,0};
    const unsigned short* ap = tb + (size_t)col * 65536 + kc0 + quad * 8;
    const unsigned short* bp = wcT + (size_t)(g * 16 + col) * 65536 + kc0 + quad * 8;
    bf16x8_t B[2], A0[2], A1[2], A2[2], A3[2];
#pragma unroll
    for (int t = 0; t < 2; t++) {
        B[t]  = *(const bf16x8_t*)(bp + t * 32);
        A0[t] = *(const bf16x8_t*)(ap + t * 32);
        A1[t] = *(const bf16x8_t*)(ap + (size_t)16 * 65536 + t * 32);
        A2[t] = *(const bf16x8_t*)(ap + (size_t)32 * 65536 + t * 32);
        A3[t] = *(const bf16x8_t*)(ap + (size_t)48 * 65536 + t * 32);
    }
#pragma unroll
    for (int c = 0; c < 4; c++) {
        int p = c & 1;
        acc0 = MFMA16(A0[p], B[p], acc0);
        acc1 = MFMA16(A1[p], B[p], acc1);
        acc2 = MFMA16(A2[p], B[p], acc2);
        acc3 = MFMA16(A3[p], B[p], acc3);
        if (c + 2 < 4) {
            int kn = (c + 2) * 32;
            B[p]  = *(const bf16x8_t*)(bp + kn);
            A0[p] = *(const bf16x8_t*)(ap + kn);
            A1[p] = *(const bf16x8_t*)(ap + (size_t)16 * 65536 + kn);
            A2[p] = *(const bf16x8_t*)(ap + (size_t)32 * 65536 + kn);
            A3[p] = *(const bf16x8_t*)(ap + (size_t)48 * 65536 + kn);
        }
    }
    f32x4_t accs[4] = {acc0, acc1, acc2, acc3};
    int j = g * 16 + col;
    float* pb = partials + blockIdx.x * 4096;
#pragma unroll
    for (int ai = 0; ai < 4; ai++)
#pragma unroll
        for (int r = 0; r < 4; r++) {
            int nn = ai * 16 + quad * 4 + r;
            pb[nn * 64 + j] = accs[ai][r];
        }
}

__global__ __launch_bounds__(256) void reduce_kernel(const float* __restrict__ partials,
                                                     const float* __restrict__ bc,
                                                     float* __restrict__ out) {
    __shared__ float red[4][64];
    int tid = threadIdx.x, lane = tid & 63, w = tid >> 6;
    int idx = blockIdx.x * 64 + lane;
    float s = 0.f;
#pragma unroll 4
    for (int c = w; c < 512; c += 4) s += partials[(size_t)c * 4096 + idx];
    red[w][lane] = s;
    __syncthreads();
    if (w == 0)
        out[idx] = red[0][lane] + red[1][lane] + red[2][lane] + red[3][lane] + bc[idx & 63];
}

// ---------------------------------------------------------------------------
extern "C" void kernel_launch(void* const* d_in, const int* in_sizes, int n_in,
                              void* d_out, int out_size, void* d_ws, size_t ws_size,
                              hipStream_t stream) {
    const float* states     = (const float*)d_in[0]; // [64][512][1024]
    const float* output_set = (const float*)d_in[1]; // [64][1024]
    const float* Wo         = (const float*)d_in[2]; // [2048][1024]
    const float* bo         = (const float*)d_in[3]; // [1024]
    const float* Wc         = (const float*)d_in[4]; // [65536][64]
    const float* bc         = (const float*)d_in[5]; // [64]
    float* out = (float*)d_out;                      // [64][64]

    char* ws = (char*)d_ws;
    // ws footprint ~40.6 MB. parts ALIASES attnf (disjoint lifetimes).
    float*          attnf = (float*)ws;                                       // 8 MB
    float*          parts = (float*)ws;                                       // 8 MB (reuses attnf)
    unsigned short* attnb = (unsigned short*)(ws + (8u  << 20));              // 4 MB
    unsigned short* mixb  = (unsigned short*)(ws + (12u << 20));              // 8 MB
    unsigned short* tb    = (unsigned short*)(ws + (20u << 20));              // 8 MB
    unsigned short* woT   = (unsigned short*)(ws + (28u << 20));              // 4 MB
    unsigned short* osb   = (unsigned short*)(ws + (32u << 20));              // 128 KB
    unsigned short* wcT   = (unsigned short*)(ws + (32u << 20) + (1u << 18)); // 8 MB
    float*          obuf  = (float*)(ws + (40u << 20) + (1u << 18));          // 256 KB

    cvt_kernel<<<dim3(IOdim * Hdim / 256), dim3(256), 0, stream>>>(output_set, osb, IOdim * Hdim);
    transpose_cvt<<<dim3(Hdim / 32, 2048 / 32), dim3(32, 8), 0, stream>>>(Wo, woT, 2048, Hdim);
    transpose_cvt<<<dim3(64 / 32, 65536 / 32), dim3(32, 8), 0, stream>>>(Wc, wcT, 65536, 64);
    ob_kernel<<<dim3(Hdim / 64), dim3(256), 0, stream>>>(osb, woT, bo, obuf);
    scores_kernel<<<dim3(Sdim / 64, Nbat), dim3(256), 0, stream>>>(states, osb, attnf);
    softmax_kernel<<<dim3(Nbat * IOdim / 4), dim3(256), 0, stream>>>(attnf, attnb);
    mix_kernel<<<dim3(Hdim / 64, Nbat), dim3(256), 0, stream>>>(states, attnb, mixb);
    out_gemm<<<dim3(Hdim / 64, Nbat * IOdim / 128), dim3(256), 0, stream>>>(mixb, woT, obuf, tb);
    final_gemm<<<dim3(512), dim3(256), 0, stream>>>(tb, wcT, parts);
    reduce_kernel<<<dim3(64), dim3(256), 0, stream>>>(parts, bc, out);
}